// Round 9
// baseline (1671.886 us; speedup 1.0000x reference)
//
#include <hip/hip_runtime.h>

#define B_ 64
#define T_ 128
#define D_ 1024
#define K2_ 2048
#define G_ 4096
#define SLOTW 65664   // u16 per ring slot: 128 KiB payload + 256 B anti-prefetch pad

typedef __attribute__((ext_vector_type(8))) short bf16x8;
typedef __attribute__((ext_vector_type(4))) float f32x4;
typedef unsigned short u16;
typedef unsigned long long u64;

#define FREADY 0x0101010101010101ULL
// u64-granular flag group offset: 64 producers (cg) x 8 wave-bytes each.
// 512 groups total = 256 KiB — MUST match the carve + zeroing below.
#define FOFF(i, L, rg) ((((size_t)(i) * 2 + (L)) * 2 + (rg)) * 64)

__device__ __forceinline__ u16 f2bf(float f) {
  unsigned int u = __float_as_uint(f);
  u += 0x7FFF + ((u >> 16) & 1);   // round-to-nearest-even
  return (u16)(u >> 16);
}

__device__ __forceinline__ float fast_sigmoid(float x) {
  return 1.f / (1.f + __expf(-x));
}
__device__ __forceinline__ float fast_tanh(float x) {
  float e = __expf(-2.f * fabsf(x));
  float t = (1.f - e) / (1.f + e);
  return copysignf(t, x);
}

// Write-through store (sc0 sc1): lands at IF, never dirty in any L2, so
// plain cached loads of this (never-reused) address are safe everywhere.
__device__ __forceinline__ void store4_wt(u16* addr, unsigned v) {
  asm volatile("global_store_dword %0, %1, off sc0 sc1"
               :: "v"((void*)addr), "v"(v) : "memory");
}
__device__ __forceinline__ void store1_wt(unsigned char* addr, unsigned v) {
  asm volatile("global_store_byte %0, %1, off sc0 sc1"
               :: "v"((void*)addr), "v"(v) : "memory");
}

// Pair-pack two adjacent bf16 (even tid = low half) and store 4B write-through.
__device__ __forceinline__ void store_pair_wt(u16* base, size_t soff, u16 v, int tid) {
  unsigned other = __shfl_xor((unsigned)v, 1);
  if (!(tid & 1))
    store4_wt(base + soff, (unsigned)v | (other << 16));
}

// Wt[n][k] = bf16(W[k][n]);  W:[2048][4096] f32, Wt:[4096][2048] bf16
__global__ __launch_bounds__(256) void transpose_w(const float* __restrict__ W,
                                                   u16* __restrict__ Wt) {
  __shared__ u16 tile[64][65];
  int bn = blockIdx.x & 63;
  int bk = blockIdx.x >> 6;
  int n0 = bn * 64, k0 = bk * 64;
  for (int i = threadIdx.x; i < 4096; i += 256) {
    int r = i >> 6, c = i & 63;
    tile[c][r] = f2bf(W[(size_t)(k0 + r) * G_ + n0 + c]);
  }
  __syncthreads();
  for (int i = threadIdx.x; i < 4096; i += 256) {
    int r = i >> 6, c = i & 63;
    Wt[(size_t)(n0 + r) * K2_ + k0 + c] = tile[r][c];
  }
}

// xg[(t*B+b)*D + d] = bf16(emb[inputs[b][t]][d])
__global__ __launch_bounds__(256) void gather_x(const int* __restrict__ inputs,
                                                const float* __restrict__ emb,
                                                u16* __restrict__ xg) {
  int idx = blockIdx.x * 256 + threadIdx.x;
  int d4 = idx & 255;
  int tb = idx >> 8;
  int t = tb >> 6, b = tb & 63;
  int tok = inputs[b * T_ + t];
  float4 v = ((const float4*)(emb + (size_t)tok * D_))[d4];
  u64 pk = (u64)f2bf(v.x)
         | ((u64)f2bf(v.y) << 16)
         | ((u64)f2bf(v.z) << 32)
         | ((u64)f2bf(v.w) << 48);
  *(u64*)(xg + (size_t)tb * D_ + d4 * 4) = pk;
}

__global__ void zero_buf(uint4* p, int n) {
  int i = blockIdx.x * blockDim.x + threadIdx.x;
  if (i < n) p[i] = make_uint4(0u, 0u, 0u, 0u);
}

// Persistent pipelined 2-layer LSTM. 256 blocks x 512 threads, 1 block/CU.
// Blocks [0,128): layer 0 (t=i); [128,256): layer 1 (t=i-1).
// T-deep write-through rings + cached consumers (r6). Zero-RMW signaling:
// per-(block,wave) byte flags at IF, consumer 64-lane gather poll. No
// aggregation tree, no global barrier in the main loop.
__global__ __launch_bounds__(512, 2) void lstm_persist(
    const u16* wt1, const u16* wt2,
    const u16* __restrict__ xg,
    u16* h1buf, u16* h1n, u16* h2buf,
    const u16* __restrict__ zbuf,
    const float* __restrict__ b1, const float* __restrict__ b2,
    const int* __restrict__ lens, float* __restrict__ out,
    int* bar, unsigned char* flags) {
  __shared__ __attribute__((aligned(16))) float part[8][64][36];
  __shared__ __attribute__((aligned(16))) float gsum[64][36];
  const int blk = blockIdx.x;
  const int L = blk >> 7;
  const int lb = blk & 127;
  const int rg = lb & 1;
  const int cg = lb >> 1;
  const int tid = threadIdx.x;
  const int lane = tid & 63;
  const int wv = tid >> 6;
  const int dc = lane & 15;
  const int kq = lane >> 4;

  const u16* wt = L ? wt2 : wt1;
  const float* bias = L ? b2 : b1;

  // register-resident weights: 4 gates x 8 k-steps of bf16x8 = 128 regs
  bf16x8 wreg[4][8];
  {
    const u16* wb = wt + (size_t)(cg * 16 + dc) * K2_ + wv * 256 + kq * 8;
    #pragma unroll
    for (int g = 0; g < 4; ++g)
      #pragma unroll
      for (int ks = 0; ks < 8; ++ks)
        wreg[g][ks] = *(const bf16x8*)(wb + (size_t)g * D_ * K2_ + ks * 32);
  }
  #pragma unroll
  for (int g = 0; g < 4; ++g)
    #pragma unroll
    for (int ks = 0; ks < 8; ++ks)
      asm volatile("" : "+v"(wreg[g][ks]));   // pin: no reload inside loop

  const int crow = tid >> 4;          // 0..31
  const int cdc = tid & 15;
  const int grow = rg * 32 + crow;
  const int dcol = cg * 16 + cdc;
  const int len_r = lens[grow];
  float bias_g[4];
  #pragma unroll
  for (int g = 0; g < 4; ++g) bias_g[g] = bias[g * D_ + dcol];
  float creg = 0.f, hreg = 0.f, outreg = 0.f;

  const int r0 = rg * 32 + (lane & 15);
  const int koff = (wv & 3) * 256 + kq * 8;

  // ---- startup grid barrier (weights must be read by ALL blocks before any
  // ring write aliases them), then one-time agent-acquire (L1/L2 invalidate
  // of wt-alias lines cached during the weight load) ----
  __syncthreads();
  if (tid == 0) {
    int a = __hip_atomic_fetch_add(bar + (size_t)(blk & 7) * 32, 1,
                                   __ATOMIC_RELAXED, __HIP_MEMORY_SCOPE_AGENT);
    if (a == 31) {
      int r = __hip_atomic_fetch_add(bar + 8 * 32, 1,
                                     __ATOMIC_RELAXED, __HIP_MEMORY_SCOPE_AGENT);
      if (r == 7)
        __hip_atomic_store(bar + 9 * 32, 1,
                           __ATOMIC_RELAXED, __HIP_MEMORY_SCOPE_AGENT);
    }
    while (!__hip_atomic_load(bar + 9 * 32,
                              __ATOMIC_RELAXED, __HIP_MEMORY_SCOPE_AGENT))
      __builtin_amdgcn_s_sleep(1);
  }
  __syncthreads();
  __builtin_amdgcn_fence(__ATOMIC_ACQUIRE, "agent");

  const u64* fbase = (const u64*)flags;

  for (int i = 0; i <= 128; ++i) {
    const bool active = L ? (i >= 1) : (i < 128);
    const int t = L ? i - 1 : i;
    if (active) {
      // dependency pickup: wave 0, lane l polls producer block (rg, cg=l)'s
      // 8 wave-bytes as one u64. Group A = layer-0 flags @ i-1 (own h1buf
      // for L0; h1n for L1). Group B (L1, i>=2) = own-layer flags @ i-1.
      if (wv == 0 && i >= 1) {
        const u64* pA = fbase + FOFF(i - 1, 0, rg) + lane;
        const u64* pB = fbase + FOFF(i - 1, 1, rg) + lane;
        const bool needB = (L == 1 && i >= 2);
        bool okA = false, okB = !needB;
        for (;;) {
          if (!okA)
            okA = (__hip_atomic_load(pA, __ATOMIC_RELAXED,
                                     __HIP_MEMORY_SCOPE_AGENT) == FREADY);
          if (!okB)
            okB = (__hip_atomic_load(pB, __ATOMIC_RELAXED,
                                     __HIP_MEMORY_SCOPE_AGENT) == FREADY);
          if (__all(okA && okB)) break;
          __builtin_amdgcn_s_sleep(2);
        }
      }
      __syncthreads();

      // per-iteration source/destination slots (plain cached loads)
      const u16* xsrc; const u16* hsrc;
      u16* w_h1n = nullptr; u16* w_h1b = nullptr; u16* w_h2b = nullptr;
      if (L == 0) {
        xsrc = xg + (size_t)t * (B_ * D_);
        hsrc = (i == 0) ? zbuf : h1buf + (size_t)(i - 1) * SLOTW;
        w_h1n = h1n + (size_t)i * SLOTW;
        w_h1b = h1buf + (size_t)i * SLOTW;
      } else {
        xsrc = h1n + (size_t)(i - 1) * SLOTW;
        hsrc = (i <= 1) ? zbuf : h2buf + (size_t)(i - 2) * SLOTW;
        w_h2b = h2buf + (size_t)(i - 1) * SLOTW;
      }
      const u16* src = (wv < 4) ? xsrc : hsrc;
      const u16* a0p = src + (size_t)r0 * D_ + koff;

      f32x4 acc[2][4];
      #pragma unroll
      for (int rt = 0; rt < 2; ++rt)
        #pragma unroll
        for (int g = 0; g < 4; ++g)
          acc[rt][g] = (f32x4){0.f, 0.f, 0.f, 0.f};

      #pragma unroll
      for (int ks = 0; ks < 8; ++ks) {
        bf16x8 a0 = *(const bf16x8*)(a0p + ks * 32);
        bf16x8 a1 = *(const bf16x8*)(a0p + 16 * D_ + ks * 32);
        #pragma unroll
        for (int g = 0; g < 4; ++g) {
          acc[0][g] = __builtin_amdgcn_mfma_f32_16x16x32_bf16(a0, wreg[g][ks], acc[0][g], 0, 0, 0);
          acc[1][g] = __builtin_amdgcn_mfma_f32_16x16x32_bf16(a1, wreg[g][ks], acc[1][g], 0, 0, 0);
        }
      }

      // partials to LDS: D-layout col = lane&15, row = kq*4 + r
      #pragma unroll
      for (int rt = 0; rt < 2; ++rt)
        #pragma unroll
        for (int g = 0; g < 4; ++g)
          *(f32x4*)&part[wv][g * 16 + dc][rt * 16 + kq * 4] = acc[rt][g];
      __syncthreads();

      // 8-way k-reduction
      {
        const int rcol = tid >> 3;
        const int rrow = (tid & 7) * 4;
        f32x4 s = *(const f32x4*)&part[0][rcol][rrow];
        #pragma unroll
        for (int w = 1; w < 8; ++w) s += *(const f32x4*)&part[w][rcol][rrow];
        *(f32x4*)&gsum[rcol][rrow] = s;
      }
      __syncthreads();

      // fused LSTM cell, one element per thread
      {
        float gi = gsum[cdc][crow] + bias_g[0];
        float gj = gsum[16 + cdc][crow] + bias_g[1];
        float gf = gsum[32 + cdc][crow] + bias_g[2];
        float go = gsum[48 + cdc][crow] + bias_g[3];
        float is = fast_sigmoid(gi);
        float fs = fast_sigmoid(gf);
        float os = fast_sigmoid(go);
        float jt = fast_tanh(gj);
        float c_new = creg * fs + is * jt;
        float h_new = fast_tanh(c_new) * os;
        bool m = t < len_r;
        if (m) { creg = c_new; hreg = h_new; }
        size_t soff = (size_t)grow * D_ + dcol;
        if (L == 0) {
          store_pair_wt(w_h1n, soff, f2bf(h_new), tid);   // raw h1n -> layer 1
          store_pair_wt(w_h1b, soff, f2bf(hreg), tid);    // masked state
        } else {
          store_pair_wt(w_h2b, soff, f2bf(hreg), tid);
          if (m) outreg += h_new;
        }
      }

      // per-wave arrival: drain THIS wave's stores, then lane 0 stores the
      // wave's flag byte. No RMW, no block barrier, no aggregation.
      asm volatile("s_waitcnt vmcnt(0)" ::: "memory");
      if (lane == 0 && !(L == 1 && i == 128)) {
        unsigned char* fb = flags + (FOFF(i, L, rg) + cg) * 8 + wv;
        store1_wt(fb, 1u);
      }
    }
  }
  if (L == 1) out[(size_t)grow * D_ + dcol] = outreg;
}

extern "C" void kernel_launch(void* const* d_in, const int* in_sizes, int n_in,
                              void* d_out, int out_size, void* d_ws, size_t ws_size,
                              hipStream_t stream) {
  const int* inputs  = (const int*)d_in[0];
  const int* lengths = (const int*)d_in[1];
  const float* emb   = (const float*)d_in[2];
  const float* W1    = (const float*)d_in[3];
  const float* b1    = (const float*)d_in[4];
  const float* W2    = (const float*)d_in[5];
  const float* b2    = (const float*)d_in[6];
  float* out = (float*)d_out;

  // workspace carve (~64.5 MiB total; rings alias the one-shot wt buffers)
  char* p = (char*)d_ws;
  u16* h1buf = (u16*)p; p += (size_t)T_ * SLOTW * 2;   // 16.03 MiB (aliases wt1)
  u16* h1n   = (u16*)p; p += (size_t)T_ * SLOTW * 2;   // 16.03 MiB (aliases wt2)
  u16* h2buf = (u16*)p; p += (size_t)T_ * SLOTW * 2;   // 16.03 MiB
  u16* xg    = (u16*)p; p += (size_t)T_ * B_ * D_ * 2; // 16 MiB
  u16* zbuf  = (u16*)p; p += (size_t)B_ * D_ * 2;      // 128 KiB (zeros)
  int* bar   = (int*)p; p += 2048;                     // 2 KiB startup lines
  // flags: 512 groups (i:128 x L:2 x rg:2) x 64 producers x 8 wave-bytes
  unsigned char* flags = (unsigned char*)p; p += (size_t)512 * 64 * 8; // 256 KiB
  u16* wt1 = h1buf;   // weights read once, pre-startup-barrier
  u16* wt2 = h1n;

  hipLaunchKernelGGL(transpose_w, dim3(2048), dim3(256), 0, stream, W1, wt1);
  hipLaunchKernelGGL(transpose_w, dim3(2048), dim3(256), 0, stream, W2, wt2);
  hipLaunchKernelGGL(gather_x, dim3(8192), dim3(256), 0, stream, inputs, emb, xg);
  // zero zbuf + bar + flags contiguously:
  // (131072 + 2048 + 262144) / 16 = 24704 uint4
  hipLaunchKernelGGL(zero_buf, dim3(97), dim3(256), 0, stream, (uint4*)zbuf, 24704);

  hipLaunchKernelGGL(lstm_persist, dim3(256), dim3(512), 0, stream,
                     wt1, wt2, xg, h1buf, h1n, h2buf, zbuf, b1, b2, lengths, out,
                     bar, flags);
}

// Round 10
// 936.502 us; speedup vs baseline: 1.7852x; 1.7852x over previous
//
#include <hip/hip_runtime.h>

#define B_ 64
#define T_ 128
#define D_ 1024
#define K2_ 2048
#define G_ 4096
#define SLOTW 65664   // u16 per ring slot: 128 KiB payload + 256 B anti-prefetch pad

typedef __attribute__((ext_vector_type(8))) short bf16x8;
typedef __attribute__((ext_vector_type(4))) float f32x4;
typedef unsigned short u16;
typedef unsigned long long u64;

__device__ __forceinline__ u16 f2bf(float f) {
  unsigned int u = __float_as_uint(f);
  u += 0x7FFF + ((u >> 16) & 1);   // round-to-nearest-even
  return (u16)(u >> 16);
}

__device__ __forceinline__ float fast_sigmoid(float x) {
  return 1.f / (1.f + __expf(-x));
}
__device__ __forceinline__ float fast_tanh(float x) {
  float e = __expf(-2.f * fabsf(x));
  float t = (1.f - e) / (1.f + e);
  return copysignf(t, x);
}

// Write-through store (sc0 sc1): lands at IF, never dirty in any L2, so
// plain cached loads of this (never-reused) address are safe everywhere.
__device__ __forceinline__ void store4_wt(u16* addr, unsigned v) {
  asm volatile("global_store_dword %0, %1, off sc0 sc1"
               :: "v"((void*)addr), "v"(v) : "memory");
}

// Pair-pack two adjacent bf16 (even tid = low half) and store 4B write-through.
__device__ __forceinline__ void store_pair_wt(u16* base, size_t soff, u16 v, int tid) {
  unsigned other = __shfl_xor((unsigned)v, 1);
  if (!(tid & 1))
    store4_wt(base + soff, (unsigned)v | (other << 16));
}

// Wt[n][k] = bf16(W[k][n]);  W:[2048][4096] f32, Wt:[4096][2048] bf16
__global__ __launch_bounds__(256) void transpose_w(const float* __restrict__ W,
                                                   u16* __restrict__ Wt) {
  __shared__ u16 tile[64][65];
  int bn = blockIdx.x & 63;
  int bk = blockIdx.x >> 6;
  int n0 = bn * 64, k0 = bk * 64;
  for (int i = threadIdx.x; i < 4096; i += 256) {
    int r = i >> 6, c = i & 63;
    tile[c][r] = f2bf(W[(size_t)(k0 + r) * G_ + n0 + c]);
  }
  __syncthreads();
  for (int i = threadIdx.x; i < 4096; i += 256) {
    int r = i >> 6, c = i & 63;
    Wt[(size_t)(n0 + r) * K2_ + k0 + c] = tile[r][c];
  }
}

// xg[(t*B+b)*D + d] = bf16(emb[inputs[b][t]][d])
__global__ __launch_bounds__(256) void gather_x(const int* __restrict__ inputs,
                                                const float* __restrict__ emb,
                                                u16* __restrict__ xg) {
  int idx = blockIdx.x * 256 + threadIdx.x;
  int d4 = idx & 255;
  int tb = idx >> 8;
  int t = tb >> 6, b = tb & 63;
  int tok = inputs[b * T_ + t];
  float4 v = ((const float4*)(emb + (size_t)tok * D_))[d4];
  u64 pk = (u64)f2bf(v.x)
         | ((u64)f2bf(v.y) << 16)
         | ((u64)f2bf(v.z) << 32)
         | ((u64)f2bf(v.w) << 48);
  *(u64*)(xg + (size_t)tb * D_ + d4 * 4) = pk;
}

__global__ void zero_buf(uint4* p, int n) {
  int i = blockIdx.x * blockDim.x + threadIdx.x;
  if (i < n) p[i] = make_uint4(0u, 0u, 0u, 0u);
}

// bar line map (128-B lines, int index = line*32):
//  0..7 startup cnt   8 startup root   9 startup done
//  per-(L,rg,i) group: 8 cnt lines (8 arrivals each) + root(8). Consumers
//  poll root >= 8 directly (no done hop).
#define GRPBASE(L, rg, i) (16 + (((L) * 2 + (rg)) * 129 + (i)) * 9)

__device__ __forceinline__ void poll_root(const int* bar, int base) {
  while (__hip_atomic_load(bar + (size_t)(base + 8) * 32,
                           __ATOMIC_RELAXED, __HIP_MEMORY_SCOPE_AGENT) < 8)
    __builtin_amdgcn_s_sleep(1);
}

// Persistent pipelined 2-layer LSTM. 256 blocks x 512 threads, 1 block/CU.
// Blocks [0,128): layer 0 (t=i); [128,256): layer 1 (t=i-1).
// T-deep write-through rings + cached consumers (r6 structure). Barriers:
// per-(L,rg) groups of 64 blocks, 8x8 arrival tree, direct root poll.
__global__ __launch_bounds__(512, 2) void lstm_persist(
    const u16* wt1, const u16* wt2,
    const u16* __restrict__ xg,
    u16* h1buf, u16* h1n, u16* h2buf,
    const u16* __restrict__ zbuf,
    const float* __restrict__ b1, const float* __restrict__ b2,
    const int* __restrict__ lens, float* __restrict__ out,
    int* bar) {
  __shared__ __attribute__((aligned(16))) float part[8][64][36];
  __shared__ __attribute__((aligned(16))) float gsum[64][36];
  const int blk = blockIdx.x;
  const int L = blk >> 7;
  const int lb = blk & 127;
  const int rg = lb & 1;
  const int cg = lb >> 1;
  const int tid = threadIdx.x;
  const int lane = tid & 63;
  const int wv = tid >> 6;
  const int dc = lane & 15;
  const int kq = lane >> 4;

  const u16* wt = L ? wt2 : wt1;
  const float* bias = L ? b2 : b1;

  // register-resident weights: 4 gates x 8 k-steps of bf16x8 = 128 regs
  bf16x8 wreg[4][8];
  {
    const u16* wb = wt + (size_t)(cg * 16 + dc) * K2_ + wv * 256 + kq * 8;
    #pragma unroll
    for (int g = 0; g < 4; ++g)
      #pragma unroll
      for (int ks = 0; ks < 8; ++ks)
        wreg[g][ks] = *(const bf16x8*)(wb + (size_t)g * D_ * K2_ + ks * 32);
  }
  #pragma unroll
  for (int g = 0; g < 4; ++g)
    #pragma unroll
    for (int ks = 0; ks < 8; ++ks)
      asm volatile("" : "+v"(wreg[g][ks]));   // pin: no reload inside loop

  const int crow = tid >> 4;          // 0..31
  const int cdc = tid & 15;
  const int grow = rg * 32 + crow;
  const int dcol = cg * 16 + cdc;
  const int len_r = lens[grow];
  float bias_g[4];
  #pragma unroll
  for (int g = 0; g < 4; ++g) bias_g[g] = bias[g * D_ + dcol];
  float creg = 0.f, hreg = 0.f, outreg = 0.f;

  const int r0 = rg * 32 + (lane & 15);
  const int koff = (wv & 3) * 256 + kq * 8;

  // ---- startup grid barrier (weights must be read by ALL blocks before any
  // ring write aliases them), then one-time agent-acquire (L1/L2 invalidate
  // of wt-alias lines cached during the weight load) ----
  __syncthreads();
  if (tid == 0) {
    int a = __hip_atomic_fetch_add(bar + (size_t)(blk & 7) * 32, 1,
                                   __ATOMIC_RELAXED, __HIP_MEMORY_SCOPE_AGENT);
    if (a == 31) {
      int r = __hip_atomic_fetch_add(bar + 8 * 32, 1,
                                     __ATOMIC_RELAXED, __HIP_MEMORY_SCOPE_AGENT);
      if (r == 7)
        __hip_atomic_store(bar + 9 * 32, 1,
                           __ATOMIC_RELAXED, __HIP_MEMORY_SCOPE_AGENT);
    }
    while (!__hip_atomic_load(bar + 9 * 32,
                              __ATOMIC_RELAXED, __HIP_MEMORY_SCOPE_AGENT))
      __builtin_amdgcn_s_sleep(1);
  }
  __syncthreads();
  __builtin_amdgcn_fence(__ATOMIC_ACQUIRE, "agent");

  for (int i = 0; i <= 128; ++i) {
    const bool active = L ? (i >= 1) : (i < 128);
    const int t = L ? i - 1 : i;
    if (active) {
      // dependency wait: per-(L,rg) roots of iter i-1 (all within own rg)
      if (tid == 0 && i >= 1) {
        if (L == 0) {
          poll_root(bar, GRPBASE(0, rg, i - 1));           // own h1buf(i-1)
        } else {
          poll_root(bar, GRPBASE(0, rg, i - 1));           // h1n(i-1)
          if (i >= 2) poll_root(bar, GRPBASE(1, rg, i - 1)); // h2buf(i-2)
        }
      }
      __syncthreads();

      // per-iteration source/destination slots (plain cached loads)
      const u16* xsrc; const u16* hsrc;
      u16* w_h1n = nullptr; u16* w_h1b = nullptr; u16* w_h2b = nullptr;
      if (L == 0) {
        xsrc = xg + (size_t)t * (B_ * D_);
        hsrc = (i == 0) ? zbuf : h1buf + (size_t)(i - 1) * SLOTW;
        w_h1n = h1n + (size_t)i * SLOTW;
        w_h1b = h1buf + (size_t)i * SLOTW;
      } else {
        xsrc = h1n + (size_t)(i - 1) * SLOTW;
        hsrc = (i <= 1) ? zbuf : h2buf + (size_t)(i - 2) * SLOTW;
        w_h2b = h2buf + (size_t)(i - 1) * SLOTW;
      }
      const u16* src = (wv < 4) ? xsrc : hsrc;
      const u16* a0p = src + (size_t)r0 * D_ + koff;

      f32x4 acc[2][4];
      #pragma unroll
      for (int rt = 0; rt < 2; ++rt)
        #pragma unroll
        for (int g = 0; g < 4; ++g)
          acc[rt][g] = (f32x4){0.f, 0.f, 0.f, 0.f};

      #pragma unroll
      for (int ks = 0; ks < 8; ++ks) {
        bf16x8 a0 = *(const bf16x8*)(a0p + ks * 32);
        bf16x8 a1 = *(const bf16x8*)(a0p + 16 * D_ + ks * 32);
        #pragma unroll
        for (int g = 0; g < 4; ++g) {
          acc[0][g] = __builtin_amdgcn_mfma_f32_16x16x32_bf16(a0, wreg[g][ks], acc[0][g], 0, 0, 0);
          acc[1][g] = __builtin_amdgcn_mfma_f32_16x16x32_bf16(a1, wreg[g][ks], acc[1][g], 0, 0, 0);
        }
      }

      // partials to LDS: D-layout col = lane&15, row = kq*4 + r
      #pragma unroll
      for (int rt = 0; rt < 2; ++rt)
        #pragma unroll
        for (int g = 0; g < 4; ++g)
          *(f32x4*)&part[wv][g * 16 + dc][rt * 16 + kq * 4] = acc[rt][g];
      __syncthreads();

      // 8-way k-reduction
      {
        const int rcol = tid >> 3;
        const int rrow = (tid & 7) * 4;
        f32x4 s = *(const f32x4*)&part[0][rcol][rrow];
        #pragma unroll
        for (int w = 1; w < 8; ++w) s += *(const f32x4*)&part[w][rcol][rrow];
        *(f32x4*)&gsum[rcol][rrow] = s;
      }
      __syncthreads();

      // fused LSTM cell, one element per thread
      {
        float gi = gsum[cdc][crow] + bias_g[0];
        float gj = gsum[16 + cdc][crow] + bias_g[1];
        float gf = gsum[32 + cdc][crow] + bias_g[2];
        float go = gsum[48 + cdc][crow] + bias_g[3];
        float is = fast_sigmoid(gi);
        float fs = fast_sigmoid(gf);
        float os = fast_sigmoid(go);
        float jt = fast_tanh(gj);
        float c_new = creg * fs + is * jt;
        float h_new = fast_tanh(c_new) * os;
        bool m = t < len_r;
        if (m) { creg = c_new; hreg = h_new; }
        size_t soff = (size_t)grow * D_ + dcol;
        if (L == 0) {
          store_pair_wt(w_h1n, soff, f2bf(h_new), tid);   // raw h1n -> layer 1
          store_pair_wt(w_h1b, soff, f2bf(hreg), tid);    // masked state
        } else {
          store_pair_wt(w_h2b, soff, f2bf(hreg), tid);
          if (m) outreg += h_new;
        }
      }

      // drain write-through stores (all waves), then tid0 signals arrival:
      // 8x8 tree within the (L,rg) group of 64 blocks — no done hop.
      asm volatile("s_waitcnt vmcnt(0)" ::: "memory");
      __syncthreads();
      if (tid == 0 && !(L == 1 && i == 128)) {
        int base = GRPBASE(L, rg, i);
        int a = __hip_atomic_fetch_add(bar + (size_t)(base + (cg & 7)) * 32, 1,
                                       __ATOMIC_RELAXED, __HIP_MEMORY_SCOPE_AGENT);
        if (a == 7)
          __hip_atomic_fetch_add(bar + (size_t)(base + 8) * 32, 1,
                                 __ATOMIC_RELAXED, __HIP_MEMORY_SCOPE_AGENT);
      }
    }
  }
  if (L == 1) out[(size_t)grow * D_ + dcol] = outreg;
}

extern "C" void kernel_launch(void* const* d_in, const int* in_sizes, int n_in,
                              void* d_out, int out_size, void* d_ws, size_t ws_size,
                              hipStream_t stream) {
  const int* inputs  = (const int*)d_in[0];
  const int* lengths = (const int*)d_in[1];
  const float* emb   = (const float*)d_in[2];
  const float* W1    = (const float*)d_in[3];
  const float* b1    = (const float*)d_in[4];
  const float* W2    = (const float*)d_in[5];
  const float* b2    = (const float*)d_in[6];
  float* out = (float*)d_out;

  // workspace carve (~64.8 MiB total; rings alias the one-shot wt buffers)
  char* p = (char*)d_ws;
  u16* h1buf = (u16*)p; p += (size_t)T_ * SLOTW * 2;   // 16.03 MiB (aliases wt1)
  u16* h1n   = (u16*)p; p += (size_t)T_ * SLOTW * 2;   // 16.03 MiB (aliases wt2)
  u16* h2buf = (u16*)p; p += (size_t)T_ * SLOTW * 2;   // 16.03 MiB
  u16* xg    = (u16*)p; p += (size_t)T_ * B_ * D_ * 2; // 16 MiB
  u16* zbuf  = (u16*)p; p += (size_t)B_ * D_ * 2;      // 128 KiB (zeros)
  int* bar   = (int*)p; p += (size_t)4672 * 128;       // 584 KiB barrier lines
  u16* wt1 = h1buf;   // weights read once, pre-startup-barrier
  u16* wt2 = h1n;

  hipLaunchKernelGGL(transpose_w, dim3(2048), dim3(256), 0, stream, W1, wt1);
  hipLaunchKernelGGL(transpose_w, dim3(2048), dim3(256), 0, stream, W2, wt2);
  hipLaunchKernelGGL(gather_x, dim3(8192), dim3(256), 0, stream, inputs, emb, xg);
  // zero zbuf + bar contiguously: (131072 + 598016)/16 = 45568 uint4
  hipLaunchKernelGGL(zero_buf, dim3(178), dim3(256), 0, stream, (uint4*)zbuf, 45568);

  hipLaunchKernelGGL(lstm_persist, dim3(256), dim3(512), 0, stream,
                     wt1, wt2, xg, h1buf, h1n, h2buf, zbuf, b1, b2, lengths, out,
                     bar);
}

// Round 11
// 889.353 us; speedup vs baseline: 1.8799x; 1.0530x over previous
//
#include <hip/hip_runtime.h>

#define B_ 64
#define T_ 128
#define D_ 1024
#define K2_ 2048
#define G_ 4096
#define SLOTW 65664   // u16 per ring slot: 128 KiB payload + 256 B anti-prefetch pad

typedef __attribute__((ext_vector_type(8))) short bf16x8;
typedef __attribute__((ext_vector_type(4))) float f32x4;
typedef unsigned short u16;
typedef unsigned long long u64;

__device__ __forceinline__ u16 f2bf(float f) {
  unsigned int u = __float_as_uint(f);
  u += 0x7FFF + ((u >> 16) & 1);   // round-to-nearest-even
  return (u16)(u >> 16);
}

__device__ __forceinline__ float fast_sigmoid(float x) {
  return 1.f / (1.f + __expf(-x));
}
__device__ __forceinline__ float fast_tanh(float x) {
  float e = __expf(-2.f * fabsf(x));
  float t = (1.f - e) / (1.f + e);
  return copysignf(t, x);
}

// Write-through store (sc0 sc1): lands at IF, never dirty in any L2, so
// plain cached loads of this (never-reused) address are safe everywhere.
__device__ __forceinline__ void store4_wt(u16* addr, unsigned v) {
  asm volatile("global_store_dword %0, %1, off sc0 sc1"
               :: "v"((void*)addr), "v"(v) : "memory");
}

// Pair-pack two adjacent bf16 (even tid = low half) and store 4B write-through.
__device__ __forceinline__ void store_pair_wt(u16* base, size_t soff, u16 v, int tid) {
  unsigned other = __shfl_xor((unsigned)v, 1);
  if (!(tid & 1))
    store4_wt(base + soff, (unsigned)v | (other << 16));
}

// Wt[n][k] = bf16(W[k][n]);  W:[2048][4096] f32, Wt:[4096][2048] bf16
__global__ __launch_bounds__(256) void transpose_w(const float* __restrict__ W,
                                                   u16* __restrict__ Wt) {
  __shared__ u16 tile[64][65];
  int bn = blockIdx.x & 63;
  int bk = blockIdx.x >> 6;
  int n0 = bn * 64, k0 = bk * 64;
  for (int i = threadIdx.x; i < 4096; i += 256) {
    int r = i >> 6, c = i & 63;
    tile[c][r] = f2bf(W[(size_t)(k0 + r) * G_ + n0 + c]);
  }
  __syncthreads();
  for (int i = threadIdx.x; i < 4096; i += 256) {
    int r = i >> 6, c = i & 63;
    Wt[(size_t)(n0 + r) * K2_ + k0 + c] = tile[r][c];
  }
}

// xg[(t*B+b)*D + d] = bf16(emb[inputs[b][t]][d])
__global__ __launch_bounds__(256) void gather_x(const int* __restrict__ inputs,
                                                const float* __restrict__ emb,
                                                u16* __restrict__ xg) {
  int idx = blockIdx.x * 256 + threadIdx.x;
  int d4 = idx & 255;
  int tb = idx >> 8;
  int t = tb >> 6, b = tb & 63;
  int tok = inputs[b * T_ + t];
  float4 v = ((const float4*)(emb + (size_t)tok * D_))[d4];
  u64 pk = (u64)f2bf(v.x)
         | ((u64)f2bf(v.y) << 16)
         | ((u64)f2bf(v.z) << 32)
         | ((u64)f2bf(v.w) << 48);
  *(u64*)(xg + (size_t)tb * D_ + d4 * 4) = pk;
}

__global__ void zero_buf(uint4* p, int n) {
  int i = blockIdx.x * blockDim.x + threadIdx.x;
  if (i < n) p[i] = make_uint4(0u, 0u, 0u, 0u);
}

// bar line map (128-B lines, int index = line*32):
//  0..7 startup cnt   8 startup root   9 startup done
//  per-(L,rg,i) group: 8 cnt lines; line g counts arrivals of producers
//  cg in [8g, 8g+8). Single level — consumers poll cnt lines directly (==8).
#define GRPBASE(L, rg, i) (16 + (((L) * 2 + (rg)) * 129 + (i)) * 8)

// Persistent pipelined 2-layer LSTM. 256 blocks x 512 threads, 1 block/CU.
// Blocks [0,128): layer 0 (t=i); [128,256): layer 1 (t=i-1).
// T-deep write-through rings + cached consumers. Per-wave fine-grained
// dependency polling (16 producers per wave) overlapped with the x-GEMM;
// single-level arrival; fused gather-reduce + cell (no gsum buffer).
__global__ __launch_bounds__(512, 2) void lstm_persist(
    const u16* wt1, const u16* wt2,
    const u16* __restrict__ xg,
    u16* h1buf, u16* h1n, u16* h2buf,
    const u16* __restrict__ zbuf,
    const float* __restrict__ b1, const float* __restrict__ b2,
    const int* __restrict__ lens, float* __restrict__ out,
    int* bar) {
  __shared__ __attribute__((aligned(16))) float part[8][64][36];
  const int blk = blockIdx.x;
  const int L = blk >> 7;
  const int lb = blk & 127;
  const int rg = lb & 1;
  const int cg = lb >> 1;
  const int tid = threadIdx.x;
  const int lane = tid & 63;
  const int wv = tid >> 6;
  const int dc = lane & 15;
  const int kq = lane >> 4;

  const u16* wt = L ? wt2 : wt1;
  const float* bias = L ? b2 : b1;

  // register-resident weights: 4 gates x 8 k-steps of bf16x8 = 128 regs
  bf16x8 wreg[4][8];
  {
    const u16* wb = wt + (size_t)(cg * 16 + dc) * K2_ + wv * 256 + kq * 8;
    #pragma unroll
    for (int g = 0; g < 4; ++g)
      #pragma unroll
      for (int ks = 0; ks < 8; ++ks)
        wreg[g][ks] = *(const bf16x8*)(wb + (size_t)g * D_ * K2_ + ks * 32);
  }
  #pragma unroll
  for (int g = 0; g < 4; ++g)
    #pragma unroll
    for (int ks = 0; ks < 8; ++ks)
      asm volatile("" : "+v"(wreg[g][ks]));   // pin: no reload inside loop

  const int crow = tid >> 4;          // 0..31
  const int cdc = tid & 15;
  const int grow = rg * 32 + crow;
  const int dcol = cg * 16 + cdc;
  const int len_r = lens[grow];
  float bias_g[4];
  #pragma unroll
  for (int g = 0; g < 4; ++g) bias_g[g] = bias[g * D_ + dcol];
  float creg = 0.f, hreg = 0.f, outreg = 0.f;

  const int r0 = rg * 32 + (lane & 15);
  const int koff = (wv & 3) * 256 + kq * 8;

  // ---- startup grid barrier (weights must be read by ALL blocks before any
  // ring write aliases them), then one-time agent-acquire (L1/L2 invalidate
  // of wt-alias lines cached during the weight load) ----
  __syncthreads();
  if (tid == 0) {
    int a = __hip_atomic_fetch_add(bar + (size_t)(blk & 7) * 32, 1,
                                   __ATOMIC_RELAXED, __HIP_MEMORY_SCOPE_AGENT);
    if (a == 31) {
      int r = __hip_atomic_fetch_add(bar + 8 * 32, 1,
                                     __ATOMIC_RELAXED, __HIP_MEMORY_SCOPE_AGENT);
      if (r == 7)
        __hip_atomic_store(bar + 9 * 32, 1,
                           __ATOMIC_RELAXED, __HIP_MEMORY_SCOPE_AGENT);
    }
    while (!__hip_atomic_load(bar + 9 * 32,
                              __ATOMIC_RELAXED, __HIP_MEMORY_SCOPE_AGENT))
      __builtin_amdgcn_s_sleep(1);
  }
  __syncthreads();
  __builtin_amdgcn_fence(__ATOMIC_ACQUIRE, "agent");

  for (int i = 0; i <= 128; ++i) {
    const bool active = L ? (i >= 1) : (i < 128);
    const int t = L ? i - 1 : i;
    if (active) {
      // per-wave fine-grained dependency wait, overlapped with x-GEMM:
      // wave wv consumes h d-slice [koff, koff+256) = producers cg in
      // [(wv&3)*16, +16) = cnt lines {2*(wv&3), 2*(wv&3)+1} of iter i-1.
      // L0: x-waves (wv<4) need nothing; h-waves poll group 0 (own layer).
      // L1: x-waves poll group 0 (h1n); h-waves poll group 1 (own h2buf).
      if (i >= 1) {
        int grp = -1;
        if (L == 0) { if (wv >= 4) grp = 0; }
        else        { grp = (wv < 4) ? 0 : (i >= 2 ? 1 : -1); }
        if (grp >= 0 && lane < 2) {
          const int* lp = bar + (size_t)(GRPBASE(grp, rg, i - 1)
                                         + 2 * (wv & 3) + lane) * 32;
          while (__hip_atomic_load(lp, __ATOMIC_RELAXED,
                                   __HIP_MEMORY_SCOPE_AGENT) < 8)
            __builtin_amdgcn_s_sleep(1);
        }
        // wave reconvergence after the divergent poll = the wave's join
      }

      // per-iteration source/destination slots (plain cached loads)
      const u16* xsrc; const u16* hsrc;
      u16* w_h1n = nullptr; u16* w_h1b = nullptr; u16* w_h2b = nullptr;
      if (L == 0) {
        xsrc = xg + (size_t)t * (B_ * D_);
        hsrc = (i == 0) ? zbuf : h1buf + (size_t)(i - 1) * SLOTW;
        w_h1n = h1n + (size_t)i * SLOTW;
        w_h1b = h1buf + (size_t)i * SLOTW;
      } else {
        xsrc = h1n + (size_t)(i - 1) * SLOTW;
        hsrc = (i <= 1) ? zbuf : h2buf + (size_t)(i - 2) * SLOTW;
        w_h2b = h2buf + (size_t)(i - 1) * SLOTW;
      }
      const u16* src = (wv < 4) ? xsrc : hsrc;
      const u16* a0p = src + (size_t)r0 * D_ + koff;

      f32x4 acc[2][4];
      #pragma unroll
      for (int rt = 0; rt < 2; ++rt)
        #pragma unroll
        for (int g = 0; g < 4; ++g)
          acc[rt][g] = (f32x4){0.f, 0.f, 0.f, 0.f};

      #pragma unroll
      for (int ks = 0; ks < 8; ++ks) {
        bf16x8 a0 = *(const bf16x8*)(a0p + ks * 32);
        bf16x8 a1 = *(const bf16x8*)(a0p + 16 * D_ + ks * 32);
        #pragma unroll
        for (int g = 0; g < 4; ++g) {
          acc[0][g] = __builtin_amdgcn_mfma_f32_16x16x32_bf16(a0, wreg[g][ks], acc[0][g], 0, 0, 0);
          acc[1][g] = __builtin_amdgcn_mfma_f32_16x16x32_bf16(a1, wreg[g][ks], acc[1][g], 0, 0, 0);
        }
      }

      // partials to LDS: D-layout col = lane&15, row = kq*4 + r
      #pragma unroll
      for (int rt = 0; rt < 2; ++rt)
        #pragma unroll
        for (int g = 0; g < 4; ++g)
          *(f32x4*)&part[wv][g * 16 + dc][rt * 16 + kq * 4] = acc[rt][g];
      __syncthreads();

      // fused gather-reduce + LSTM cell: thread (crow, cdc) sums its own
      // 8 wave-partials per gate (2-way bank aliasing = free), then applies
      // the cell. Same per-element summation order as before -> bit-identical.
      {
        float gacc[4];
        #pragma unroll
        for (int g = 0; g < 4; ++g) {
          float s = part[0][g * 16 + cdc][crow];
          #pragma unroll
          for (int w = 1; w < 8; ++w) s += part[w][g * 16 + cdc][crow];
          gacc[g] = s + bias_g[g];
        }
        float is = fast_sigmoid(gacc[0]);
        float jt = fast_tanh(gacc[1]);
        float fs = fast_sigmoid(gacc[2]);
        float os = fast_sigmoid(gacc[3]);
        float c_new = creg * fs + is * jt;
        float h_new = fast_tanh(c_new) * os;
        bool m = t < len_r;
        if (m) { creg = c_new; hreg = h_new; }
        size_t soff = (size_t)grow * D_ + dcol;
        if (L == 0) {
          store_pair_wt(w_h1n, soff, f2bf(h_new), tid);   // raw h1n -> layer 1
          store_pair_wt(w_h1b, soff, f2bf(hreg), tid);    // masked state
        } else {
          store_pair_wt(w_h2b, soff, f2bf(hreg), tid);
          if (m) outreg += h_new;
        }
      }

      // drain write-through stores (all waves), then tid0 signals arrival on
      // the single-level cnt line cg>>3 (8 producers per line).
      asm volatile("s_waitcnt vmcnt(0)" ::: "memory");
      __syncthreads();
      if (tid == 0 && !(L == 1 && i == 128))
        __hip_atomic_fetch_add(bar + (size_t)(GRPBASE(L, rg, i) + (cg >> 3)) * 32, 1,
                               __ATOMIC_RELAXED, __HIP_MEMORY_SCOPE_AGENT);
    }
  }
  if (L == 1) out[(size_t)grow * D_ + dcol] = outreg;
}

extern "C" void kernel_launch(void* const* d_in, const int* in_sizes, int n_in,
                              void* d_out, int out_size, void* d_ws, size_t ws_size,
                              hipStream_t stream) {
  const int* inputs  = (const int*)d_in[0];
  const int* lengths = (const int*)d_in[1];
  const float* emb   = (const float*)d_in[2];
  const float* W1    = (const float*)d_in[3];
  const float* b1    = (const float*)d_in[4];
  const float* W2    = (const float*)d_in[5];
  const float* b2    = (const float*)d_in[6];
  float* out = (float*)d_out;

  // workspace carve (~64.7 MiB total; rings alias the one-shot wt buffers)
  char* p = (char*)d_ws;
  u16* h1buf = (u16*)p; p += (size_t)T_ * SLOTW * 2;   // 16.03 MiB (aliases wt1)
  u16* h1n   = (u16*)p; p += (size_t)T_ * SLOTW * 2;   // 16.03 MiB (aliases wt2)
  u16* h2buf = (u16*)p; p += (size_t)T_ * SLOTW * 2;   // 16.03 MiB
  u16* xg    = (u16*)p; p += (size_t)T_ * B_ * D_ * 2; // 16 MiB
  u16* zbuf  = (u16*)p; p += (size_t)B_ * D_ * 2;      // 128 KiB (zeros)
  int* bar   = (int*)p; p += (size_t)4144 * 128;       // 518 KiB barrier lines
  u16* wt1 = h1buf;   // weights read once, pre-startup-barrier
  u16* wt2 = h1n;

  hipLaunchKernelGGL(transpose_w, dim3(2048), dim3(256), 0, stream, W1, wt1);
  hipLaunchKernelGGL(transpose_w, dim3(2048), dim3(256), 0, stream, W2, wt2);
  hipLaunchKernelGGL(gather_x, dim3(8192), dim3(256), 0, stream, inputs, emb, xg);
  // zero zbuf + bar contiguously: (131072 + 530432)/16 = 41344 uint4
  hipLaunchKernelGGL(zero_buf, dim3(162), dim3(256), 0, stream, (uint4*)zbuf, 41344);

  hipLaunchKernelGGL(lstm_persist, dim3(256), dim3(512), 0, stream,
                     wt1, wt2, xg, h1buf, h1n, h2buf, zbuf, b1, b2, lengths, out,
                     bar);
}